// Round 1
// baseline (1156.909 us; speedup 1.0000x reference)
//
#include <hip/hip_runtime.h>

// S5 associative scan, T=131072, D=256, fp32.
// combine(earlier=(Ai,Bi), later=(Aj,Bj)) = (Aj*Ai, Aj*Bi + Bj)
//
// Single-pass decoupled-lookback scan (rocPRIM/CUB style):
//   - 2048 blocks x 256 threads; each block scans a 64-row chunk held in
//     registers (4 waves x 16 rows; thread owns 4 channels as float4).
//   - ordered ticket via atomicAdd => block processing chunk n started after
//     all chunks < n => lookback is deadlock-free (every started block
//     publishes its AGG without waiting on anyone).
//   - flags: 0=invalid, 1=AGG, 2=PREFIX, published with fetch_max(release,
//     agent) so a racing AGG store can never downgrade a PREFIX.
// HBM traffic: 268 MB in + 268 MB out + ~20 MB agg/flag  (~556 MB total)
// vs 4-pass structure's ~830 MB + two latency-bound middle kernels.

#define T_TOTAL 131072
#define D_DIM   256
#define RPW     16                    // rows per wave (held in registers)
#define WAVES   4
#define RPB     (RPW * WAVES)         // 64 rows per block
#define NCHUNK  (T_TOTAL / RPB)       // 2048
#define NTHR    (WAVES * 64)          // 256 threads

#define F_NONE 0
#define F_AGG  1
#define F_PRE  2

typedef float vfloat4 __attribute__((ext_vector_type(4)));

__device__ __forceinline__ float4 nt_load4(const float* p) {
    vfloat4 t = __builtin_nontemporal_load((const vfloat4*)p);
    return make_float4(t.x, t.y, t.z, t.w);
}
__device__ __forceinline__ void nt_store4(float* p, const float4 v) {
    vfloat4 t = {v.x, v.y, v.z, v.w};
    __builtin_nontemporal_store(t, (vfloat4*)p);
}

// state (ra,rb) <- combine(earlier=state, later=(ga,gb))
__device__ __forceinline__ void append(float4& ra, float4& rb,
                                       const float4 ga, const float4 gb) {
    rb.x = fmaf(ga.x, rb.x, gb.x);  ra.x *= ga.x;
    rb.y = fmaf(ga.y, rb.y, gb.y);  ra.y *= ga.y;
    rb.z = fmaf(ga.z, rb.z, gb.z);  ra.z *= ga.z;
    rb.w = fmaf(ga.w, rb.w, gb.w);  ra.w *= ga.w;
}
// suffix-acc (aa,ab) <- combine(earlier=(ga,gb), later=acc)   [lookback walk]
__device__ __forceinline__ void prepend(float4& aa, float4& ab,
                                        const float4 ga, const float4 gb) {
    ab.x = fmaf(aa.x, gb.x, ab.x);  aa.x *= ga.x;
    ab.y = fmaf(aa.y, gb.y, ab.y);  aa.y *= ga.y;
    ab.z = fmaf(aa.z, gb.z, ab.z);  aa.z *= ga.z;
    ab.w = fmaf(aa.w, gb.w, ab.w);  aa.w *= ga.w;
}

__global__ __launch_bounds__(256) void s5_init(int* __restrict__ flags)
{
    const int i = blockIdx.x * 256 + threadIdx.x;
    if (i <= NCHUNK) flags[i] = F_NONE;   // flags[NCHUNK] doubles as ticket
}

__global__ __launch_bounds__(NTHR, 2) void s5_scan(
    const float* __restrict__ A, const float* __restrict__ Bu,
    float* __restrict__ outA, float* __restrict__ outB,
    float* __restrict__ aggA, float* __restrict__ aggB,
    float* __restrict__ preA, float* __restrict__ preB,
    int* __restrict__ flags, int* __restrict__ ticket)
{
    __shared__ float lsA[WAVES][D_DIM];   // per-wave aggregates
    __shared__ float lsB[WAVES][D_DIM];
    __shared__ float lpA[D_DIM];          // block exclusive prefix P
    __shared__ float lpB[D_DIM];
    __shared__ int   s_chunk;

    const int tid  = threadIdx.x;
    if (tid == 0) s_chunk = atomicAdd(ticket, 1);   // ordered ticket
    __syncthreads();
    const int chunk = s_chunk;
    const int wave  = tid >> 6;
    const int lane  = tid & 63;
    const int ch    = lane * 4;

    const size_t base = (size_t)(chunk * RPB + wave * RPW) * D_DIM + ch;

    // ---- load chunk into registers (fully unrolled => static indices) ----
    float4 la[RPW], lb[RPW];
    #pragma unroll
    for (int t = 0; t < RPW; ++t) {
        la[t] = nt_load4(A  + base + (size_t)t * D_DIM);
        lb[t] = nt_load4(Bu + base + (size_t)t * D_DIM);
    }

    // ---- local inclusive scan within the wave's 16 rows ----
    #pragma unroll
    for (int t = 1; t < RPW; ++t) {
        // (la[t],lb[t]) <- combine(earlier=(la[t-1],lb[t-1]), later=(la[t],lb[t]))
        lb[t].x = fmaf(la[t].x, lb[t-1].x, lb[t].x);  la[t].x *= la[t-1].x;
        lb[t].y = fmaf(la[t].y, lb[t-1].y, lb[t].y);  la[t].y *= la[t-1].y;
        lb[t].z = fmaf(la[t].z, lb[t-1].z, lb[t].z);  la[t].z *= la[t-1].z;
        lb[t].w = fmaf(la[t].w, lb[t-1].w, lb[t].w);  la[t].w *= la[t-1].w;
    }

    // ---- share wave aggregates across the block ----
    *(float4*)&lsA[wave][ch] = la[RPW - 1];
    *(float4*)&lsB[wave][ch] = lb[RPW - 1];
    __syncthreads();

    // wave's exclusive prefix within the block (aggs of waves < wave)
    float4 wpa = make_float4(1.f, 1.f, 1.f, 1.f);
    float4 wpb = make_float4(0.f, 0.f, 0.f, 0.f);
    #pragma unroll
    for (int w = 0; w < WAVES - 1; ++w) {
        if (wave > w)
            append(wpa, wpb, *(const float4*)&lsA[w][ch],
                             *(const float4*)&lsB[w][ch]);
    }

    // ---- wave 3: publish block AGGREGATE asap (successors unblock on it) ----
    if (wave == 3 && chunk > 0) {
        float4 ba = wpa, bb = wpb;                     // aggs 0..2
        append(ba, bb, la[RPW - 1], lb[RPW - 1]);      // + own wave agg
        *(float4*)(aggA + (size_t)chunk * D_DIM + ch) = ba;
        *(float4*)(aggB + (size_t)chunk * D_DIM + ch) = bb;
        __threadfence();
        if (lane == 0)
            __hip_atomic_fetch_max(&flags[chunk], F_AGG,
                                   __ATOMIC_RELEASE, __HIP_MEMORY_SCOPE_AGENT);
    }

    // ---- wave 0: lookback, then publish inclusive PREFIX ----
    if (wave == 0) {
        // block aggregate (all 4 wave aggs)
        float4 ba = make_float4(1.f, 1.f, 1.f, 1.f);
        float4 bb = make_float4(0.f, 0.f, 0.f, 0.f);
        #pragma unroll
        for (int w = 0; w < WAVES; ++w)
            append(ba, bb, *(const float4*)&lsA[w][ch],
                           *(const float4*)&lsB[w][ch]);

        // exclusive prefix P via decoupled lookback
        float4 Pa = make_float4(1.f, 1.f, 1.f, 1.f);
        float4 Pb = make_float4(0.f, 0.f, 0.f, 0.f);
        if (chunk > 0) {
            int k = chunk - 1;
            for (;;) {
                int f;
                for (;;) {
                    f = __hip_atomic_load(&flags[k], __ATOMIC_ACQUIRE,
                                          __HIP_MEMORY_SCOPE_AGENT);
                    f = __builtin_amdgcn_readfirstlane(f);
                    if (f != F_NONE) break;
                    __builtin_amdgcn_s_sleep(1);
                }
                if (f == F_AGG) {
                    const float4 ga = *(const float4*)(aggA + (size_t)k * D_DIM + ch);
                    const float4 gb = *(const float4*)(aggB + (size_t)k * D_DIM + ch);
                    prepend(Pa, Pb, ga, gb);
                    --k;
                } else {                               // F_PRE: terminal
                    const float4 ga = *(const float4*)(preA + (size_t)k * D_DIM + ch);
                    const float4 gb = *(const float4*)(preB + (size_t)k * D_DIM + ch);
                    prepend(Pa, Pb, ga, gb);
                    break;
                }
            }
        }

        // publish inclusive prefix = combine(P, blockAgg)
        float4 ia = Pa, ib = Pb;
        append(ia, ib, ba, bb);
        *(float4*)(preA + (size_t)chunk * D_DIM + ch) = ia;
        *(float4*)(preB + (size_t)chunk * D_DIM + ch) = ib;
        __threadfence();
        if (lane == 0)
            __hip_atomic_fetch_max(&flags[chunk], F_PRE,
                                   __ATOMIC_RELEASE, __HIP_MEMORY_SCOPE_AGENT);

        // share P with the other waves
        *(float4*)&lpA[ch] = Pa;
        *(float4*)&lpB[ch] = Pb;
    }
    __syncthreads();

    // ---- final exclusive prefix for this wave = combine(P, wavePrefix) ----
    float4 fpA = *(const float4*)&lpA[ch];
    float4 fpB = *(const float4*)&lpB[ch];
    append(fpA, fpB, wpa, wpb);

    // ---- apply prefix to local inclusives and store (nontemporal) ----
    #pragma unroll
    for (int t = 0; t < RPW; ++t) {
        float4 oa, ob;
        oa.x = la[t].x * fpA.x;  ob.x = fmaf(la[t].x, fpB.x, lb[t].x);
        oa.y = la[t].y * fpA.y;  ob.y = fmaf(la[t].y, fpB.y, lb[t].y);
        oa.z = la[t].z * fpA.z;  ob.z = fmaf(la[t].z, fpB.z, lb[t].z);
        oa.w = la[t].w * fpA.w;  ob.w = fmaf(la[t].w, fpB.w, lb[t].w);
        nt_store4(outA + base + (size_t)t * D_DIM, oa);
        nt_store4(outB + base + (size_t)t * D_DIM, ob);
    }
}

extern "C" void kernel_launch(void* const* d_in, const int* in_sizes, int n_in,
                              void* d_out, int out_size, void* d_ws, size_t ws_size,
                              hipStream_t stream)
{
    const float* A  = (const float*)d_in[0];
    const float* Bu = (const float*)d_in[1];
    float* outA = (float*)d_out;
    float* outB = outA + (size_t)T_TOTAL * D_DIM;

    // workspace: aggA/aggB/preA/preB (2 MB each) + flags (NCHUNK+1 ints)
    float* aggA  = (float*)d_ws;
    float* aggB  = aggA + (size_t)NCHUNK * D_DIM;
    float* preA  = aggB + (size_t)NCHUNK * D_DIM;
    float* preB  = preA + (size_t)NCHUNK * D_DIM;
    int*   flags = (int*)(preB + (size_t)NCHUNK * D_DIM);

    s5_init<<<(NCHUNK + 1 + 255) / 256, 256, 0, stream>>>(flags);
    s5_scan<<<NCHUNK, NTHR, 0, stream>>>(A, Bu, outA, outB,
                                         aggA, aggB, preA, preB,
                                         flags, flags + NCHUNK);
}

// Round 3
// 606.222 us; speedup vs baseline: 1.9084x; 1.9084x over previous
//
#include <hip/hip_runtime.h>

// S5 associative scan, T=131072, D=256, fp32.
// combine(earlier=(Ai,Bi), later=(Aj,Bj)) = (Aj*Ai, Aj*Bi + Bj)
//
// Single-pass decoupled-lookback scan with WINDOWED lookback (CUB-style):
//   - 1024 blocks x 512 threads (8 waves); each block scans a 128-row chunk
//     held in registers (16 rows/wave; thread owns 4 channels as float4).
//   - ordered ticket via atomicAdd => deadlock-free lookback.
//   - flags: 0=none, 1=AGG, 2=PREFIX, published with fetch_max(release,agent).
//   - lookback reads a 64-wide flag window per poll (lane i -> flag[k-i]),
//     ballot picks the most recent PREFIX; predecessor aggregates are
//     consumed in batches of 8 positions (parallel loads, serial combines).
// Round-1 failure mode fixed: per-hop serial walk (407 ns x 2048 hops
// = 833 us) -> window advances up to 64 chunks per round-trip.
// Round-2 fix: __hip_atomic_fence doesn't exist -> __builtin_amdgcn_fence.

#define T_TOTAL 131072
#define D_DIM   256
#define RPW     16                    // rows per wave (in registers)
#define WAVES   8
#define RPB     (RPW * WAVES)         // 128 rows per block
#define NCHUNK  (T_TOTAL / RPB)       // 1024
#define NTHR    (WAVES * 64)          // 512 threads

#define F_NONE 0
#define F_AGG  1
#define F_PRE  2

typedef float vfloat4 __attribute__((ext_vector_type(4)));

__device__ __forceinline__ float4 nt_load4(const float* p) {
    vfloat4 t = __builtin_nontemporal_load((const vfloat4*)p);
    return make_float4(t.x, t.y, t.z, t.w);
}
__device__ __forceinline__ void nt_store4(float* p, const float4 v) {
    vfloat4 t = {v.x, v.y, v.z, v.w};
    __builtin_nontemporal_store(t, (vfloat4*)p);
}

// state (ra,rb) <- combine(earlier=state, later=(ga,gb))
__device__ __forceinline__ void append(float4& ra, float4& rb,
                                       const float4 ga, const float4 gb) {
    rb.x = fmaf(ga.x, rb.x, gb.x);  ra.x *= ga.x;
    rb.y = fmaf(ga.y, rb.y, gb.y);  ra.y *= ga.y;
    rb.z = fmaf(ga.z, rb.z, gb.z);  ra.z *= ga.z;
    rb.w = fmaf(ga.w, rb.w, gb.w);  ra.w *= ga.w;
}
// suffix-acc (aa,ab) <- combine(earlier=(ga,gb), later=acc)   [lookback walk]
__device__ __forceinline__ void prepend(float4& aa, float4& ab,
                                        const float4 ga, const float4 gb) {
    ab.x = fmaf(aa.x, gb.x, ab.x);  aa.x *= ga.x;
    ab.y = fmaf(aa.y, gb.y, ab.y);  aa.y *= ga.y;
    ab.z = fmaf(aa.z, gb.z, ab.z);  aa.z *= ga.z;
    ab.w = fmaf(aa.w, gb.w, ab.w);  aa.w *= ga.w;
}

__global__ __launch_bounds__(256) void s5_init(int* __restrict__ flags)
{
    const int i = blockIdx.x * 256 + threadIdx.x;
    if (i <= NCHUNK) flags[i] = F_NONE;   // flags[NCHUNK] doubles as ticket
}

__global__ __launch_bounds__(NTHR) void s5_scan(
    const float* __restrict__ A, const float* __restrict__ Bu,
    float* __restrict__ outA, float* __restrict__ outB,
    float* __restrict__ aggA, float* __restrict__ aggB,
    float* __restrict__ preA, float* __restrict__ preB,
    int* __restrict__ flags, int* __restrict__ ticket)
{
    __shared__ float lsA[WAVES][D_DIM];   // per-wave aggregates
    __shared__ float lsB[WAVES][D_DIM];
    __shared__ float lpA[D_DIM];          // block exclusive prefix P
    __shared__ float lpB[D_DIM];
    __shared__ int   s_chunk;

    const int tid  = threadIdx.x;
    if (tid == 0) s_chunk = atomicAdd(ticket, 1);   // ordered ticket
    __syncthreads();
    const int chunk = s_chunk;
    const int wave  = tid >> 6;
    const int lane  = tid & 63;
    const int ch    = lane * 4;

    const size_t base = (size_t)(chunk * RPB + wave * RPW) * D_DIM + ch;

    // ---- load this wave's 16 rows into registers ----
    float4 la[RPW], lb[RPW];
    #pragma unroll
    for (int t = 0; t < RPW; ++t) {
        la[t] = nt_load4(A  + base + (size_t)t * D_DIM);
        lb[t] = nt_load4(Bu + base + (size_t)t * D_DIM);
    }

    // ---- local inclusive scan within the wave's rows ----
    #pragma unroll
    for (int t = 1; t < RPW; ++t) {
        lb[t].x = fmaf(la[t].x, lb[t-1].x, lb[t].x);  la[t].x *= la[t-1].x;
        lb[t].y = fmaf(la[t].y, lb[t-1].y, lb[t].y);  la[t].y *= la[t-1].y;
        lb[t].z = fmaf(la[t].z, lb[t-1].z, lb[t].z);  la[t].z *= la[t-1].z;
        lb[t].w = fmaf(la[t].w, lb[t-1].w, lb[t].w);  la[t].w *= la[t-1].w;
    }

    // ---- share wave aggregates across the block ----
    *(float4*)&lsA[wave][ch] = la[RPW - 1];
    *(float4*)&lsB[wave][ch] = lb[RPW - 1];
    __syncthreads();

    // wave's exclusive prefix within the block (aggs of waves < wave)
    float4 wpa = make_float4(1.f, 1.f, 1.f, 1.f);
    float4 wpb = make_float4(0.f, 0.f, 0.f, 0.f);
    #pragma unroll
    for (int w = 0; w < WAVES - 1; ++w) {
        if (wave > w)
            append(wpa, wpb, *(const float4*)&lsA[w][ch],
                             *(const float4*)&lsB[w][ch]);
    }

    // ---- wave 7: publish block AGGREGATE asap ----
    if (wave == WAVES - 1 && chunk > 0) {
        float4 ba = wpa, bb = wpb;                     // aggs of waves 0..6
        append(ba, bb, la[RPW - 1], lb[RPW - 1]);      // + own wave agg
        *(float4*)(aggA + (size_t)chunk * D_DIM + ch) = ba;
        *(float4*)(aggB + (size_t)chunk * D_DIM + ch) = bb;
        __threadfence();
        if (lane == 0)
            __hip_atomic_fetch_max(&flags[chunk], F_AGG,
                                   __ATOMIC_RELEASE, __HIP_MEMORY_SCOPE_AGENT);
    }

    // ---- wave 0: windowed lookback, then publish inclusive PREFIX ----
    if (wave == 0) {
        // block aggregate (all 8 wave aggs)
        float4 ba = make_float4(1.f, 1.f, 1.f, 1.f);
        float4 bb = make_float4(0.f, 0.f, 0.f, 0.f);
        #pragma unroll
        for (int w = 0; w < WAVES; ++w)
            append(ba, bb, *(const float4*)&lsA[w][ch],
                           *(const float4*)&lsB[w][ch]);

        // exclusive prefix P via windowed decoupled lookback
        float4 Pa = make_float4(1.f, 1.f, 1.f, 1.f);
        float4 Pb = make_float4(0.f, 0.f, 0.f, 0.f);
        if (chunk > 0) {
            int k = chunk - 1;
            for (;;) {
                // poll 64-wide flag window: lane i -> flag[k-i]
                const int idx = k - lane;
                int f = F_NONE;
                if (idx >= 0)
                    f = __hip_atomic_load(&flags[idx], __ATOMIC_RELAXED,
                                          __HIP_MEMORY_SCOPE_AGENT);
                const unsigned long long bpre  = __ballot(f == F_PRE);
                const unsigned long long bnone = __ballot(f == F_NONE);
                const int first_pre  = bpre  ? (__ffsll(bpre)  - 1) : 64;
                const int first_none = bnone ? (__ffsll(bnone) - 1) : 64;

                int cnt;       // positions to consume: k .. k-cnt+1
                bool isPre;    // last consumed position is a PREFIX
                if (first_pre < first_none) { cnt = first_pre + 1; isPre = true; }
                else                        { cnt = first_none;    isPre = false; }

                if (cnt == 0) { __builtin_amdgcn_s_sleep(2); continue; }

                // make predecessor agg/pre data visible (acquire, agent scope)
                __builtin_amdgcn_fence(__ATOMIC_ACQUIRE, "agent");

                // consume in batches of 8: parallel loads, serial combines
                int j = 0;
                while (j < cnt) {
                    const int n = (cnt - j < 8) ? (cnt - j) : 8;
                    float4 ga[8], gb[8];
                    #pragma unroll
                    for (int u = 0; u < 8; ++u) {
                        if (u < n) {
                            const int p = k - (j + u);
                            const bool last = isPre && (j + u == cnt - 1);
                            const float* sA = last ? preA : aggA;
                            const float* sB = last ? preB : aggB;
                            ga[u] = *(const float4*)(sA + (size_t)p * D_DIM + ch);
                            gb[u] = *(const float4*)(sB + (size_t)p * D_DIM + ch);
                        }
                    }
                    #pragma unroll
                    for (int u = 0; u < 8; ++u)
                        if (u < n) prepend(Pa, Pb, ga[u], gb[u]);
                    j += 8;
                }
                k -= cnt;
                if (isPre) break;
            }
        }

        // publish inclusive prefix = combine(P, blockAgg)
        float4 ia = Pa, ib = Pb;
        append(ia, ib, ba, bb);
        *(float4*)(preA + (size_t)chunk * D_DIM + ch) = ia;
        *(float4*)(preB + (size_t)chunk * D_DIM + ch) = ib;
        __threadfence();
        if (lane == 0)
            __hip_atomic_fetch_max(&flags[chunk], F_PRE,
                                   __ATOMIC_RELEASE, __HIP_MEMORY_SCOPE_AGENT);

        // share P with the other waves
        *(float4*)&lpA[ch] = Pa;
        *(float4*)&lpB[ch] = Pb;
    }
    __syncthreads();

    // ---- final exclusive prefix for this wave = combine(P, wavePrefix) ----
    float4 fpA = *(const float4*)&lpA[ch];
    float4 fpB = *(const float4*)&lpB[ch];
    append(fpA, fpB, wpa, wpb);

    // ---- apply prefix to local inclusives and store (nontemporal) ----
    #pragma unroll
    for (int t = 0; t < RPW; ++t) {
        float4 oa, ob;
        oa.x = la[t].x * fpA.x;  ob.x = fmaf(la[t].x, fpB.x, lb[t].x);
        oa.y = la[t].y * fpA.y;  ob.y = fmaf(la[t].y, fpB.y, lb[t].y);
        oa.z = la[t].z * fpA.z;  ob.z = fmaf(la[t].z, fpB.z, lb[t].z);
        oa.w = la[t].w * fpA.w;  ob.w = fmaf(la[t].w, fpB.w, lb[t].w);
        nt_store4(outA + base + (size_t)t * D_DIM, oa);
        nt_store4(outB + base + (size_t)t * D_DIM, ob);
    }
}

extern "C" void kernel_launch(void* const* d_in, const int* in_sizes, int n_in,
                              void* d_out, int out_size, void* d_ws, size_t ws_size,
                              hipStream_t stream)
{
    const float* A  = (const float*)d_in[0];
    const float* Bu = (const float*)d_in[1];
    float* outA = (float*)d_out;
    float* outB = outA + (size_t)T_TOTAL * D_DIM;

    // workspace: aggA/aggB/preA/preB (1 MB each) + flags (NCHUNK+1 ints)
    float* aggA  = (float*)d_ws;
    float* aggB  = aggA + (size_t)NCHUNK * D_DIM;
    float* preA  = aggB + (size_t)NCHUNK * D_DIM;
    float* preB  = preA + (size_t)NCHUNK * D_DIM;
    int*   flags = (int*)(preB + (size_t)NCHUNK * D_DIM);

    s5_init<<<(NCHUNK + 1 + 255) / 256, 256, 0, stream>>>(flags);
    s5_scan<<<NCHUNK, NTHR, 0, stream>>>(A, Bu, outA, outB,
                                         aggA, aggB, preA, preB,
                                         flags, flags + NCHUNK);
}